// Round 1
// baseline (297.875 us; speedup 1.0000x reference)
//
#include <hip/hip_runtime.h>
#include <math.h>

#define NN 512
#define CC 32
#define RR 32
#define EPSF 1e-8f

// Filter ids: 0=f00 (scalar), 1=f01 (0x1->1), 2=f02 (0x2->2), 3=f10 (1x1->0), 4=f11 (1x1->1)

struct TFNWeights {
    const float* w1[5];
    const float* b1[5];
    const float* w2[5];
    const float* b2[5];
};

__global__ __launch_bounds__(256) void tfn_kernel(
    const float* __restrict__ in0,   // [N,C,1]
    const float* __restrict__ in1,   // [N,C,3]
    const float* __restrict__ in2,   // [N,C,5]
    const float* __restrict__ rbf,   // [N,N,R]
    const float* __restrict__ rij,   // [N,N,3]
    TFNWeights W,
    float* __restrict__ out)
{
    const int a    = blockIdx.x;
    const int f    = blockIdx.y;
    const int lane = threadIdx.x & 31;   // k in layer1, c in layer2/accum
    const int bg   = threadIdx.x >> 5;   // which b within the 8-wide tile

    __shared__ float rbfs[8][32];
    __shared__ float hs[8][32];
    __shared__ float red[8][32];

    // ---- cache this filter's weight rows in registers ----
    float w1row[32], w2row[32];
    {
        const float4* w1p = (const float4*)(W.w1[f] + lane * RR);
        const float4* w2p = (const float4*)(W.w2[f] + lane * RR);
        #pragma unroll
        for (int i = 0; i < 8; ++i) {
            float4 q = w1p[i];
            w1row[4*i+0] = q.x; w1row[4*i+1] = q.y; w1row[4*i+2] = q.z; w1row[4*i+3] = q.w;
            float4 p = w2p[i];
            w2row[4*i+0] = p.x; w2row[4*i+1] = p.y; w2row[4*i+2] = p.z; w2row[4*i+3] = p.w;
        }
    }
    const float b1v = W.b1[f][lane];
    const float b2v = W.b2[f][lane];

    float acc[9];
    #pragma unroll
    for (int i = 0; i < 9; ++i) acc[i] = 0.f;

    const float Y2C = 0.28867513459481287f;  // 1/(2*sqrt(3))

    for (int tile = 0; tile < NN / 8; ++tile) {
        const int b0 = tile * 8;
        __syncthreads();
        // stage 8 rbf rows (coalesced 1 KiB)
        rbfs[bg][lane] = rbf[((size_t)a * NN + (b0 + bg)) * RR + lane];
        __syncthreads();

        // ---- layer 1: h[k=lane] = relu(b1 + rbf . w1[k,:]) ----
        float h = b1v;
        #pragma unroll
        for (int r4 = 0; r4 < 8; ++r4) {
            float4 q = *(const float4*)&rbfs[bg][r4 * 4];
            h = fmaf(q.x, w1row[4*r4+0], h);
            h = fmaf(q.y, w1row[4*r4+1], h);
            h = fmaf(q.z, w1row[4*r4+2], h);
            h = fmaf(q.w, w1row[4*r4+3], h);
        }
        hs[bg][lane] = fmaxf(h, 0.f);
        __syncthreads();

        // ---- layer 2: rad[c=lane] = b2 + h . w2[c,:] ----
        float rad = b2v;
        #pragma unroll
        for (int k4 = 0; k4 < 8; ++k4) {
            float4 q = *(const float4*)&hs[bg][k4 * 4];
            rad = fmaf(q.x, w2row[4*k4+0], rad);
            rad = fmaf(q.y, w2row[4*k4+1], rad);
            rad = fmaf(q.z, w2row[4*k4+2], rad);
            rad = fmaf(q.w, w2row[4*k4+3], rad);
        }

        const int b = b0 + bg;
        const int c = lane;

        // geometry for this pair (broadcast loads; uniform within group)
        const float x = rij[((size_t)a * NN + b) * 3 + 0];
        const float y = rij[((size_t)a * NN + b) * 3 + 1];
        const float z = rij[((size_t)a * NN + b) * 3 + 2];
        const float d2 = x*x + y*y + z*z;
        const float d  = sqrtf(d2);

        if (f == 0) {
            const float i0 = in0[b * CC + c];
            acc[0] = fmaf(rad, i0, acc[0]);
            const float i10 = in1[(b * CC + c) * 3 + 0];
            const float i11 = in1[(b * CC + c) * 3 + 1];
            const float i12 = in1[(b * CC + c) * 3 + 2];
            acc[1] = fmaf(rad, i10, acc[1]);
            acc[2] = fmaf(rad, i11, acc[2]);
            acc[3] = fmaf(rad, i12, acc[3]);
            #pragma unroll
            for (int i = 0; i < 5; ++i) {
                acc[4 + i] = fmaf(rad, in2[(b * CC + c) * 5 + i], acc[4 + i]);
            }
        } else {
            const float m = (d >= EPSF) ? 1.f : 0.f;
            const float radm = rad * m;
            const float inv = 1.f / (d + EPSF);
            const float ux = x * inv, uy = y * inv, uz = z * inv;
            if (f == 1) {
                const float t = radm * in0[b * CC + c];
                acc[0] = fmaf(t, ux, acc[0]);
                acc[1] = fmaf(t, uy, acc[1]);
                acc[2] = fmaf(t, uz, acc[2]);
            } else if (f == 2) {
                const float ir2 = 1.f / fmaxf(d2, EPSF);
                const float y20 = x * y * ir2;
                const float y21 = y * z * ir2;
                const float y22 = (2.f*z*z - x*x - y*y) * ir2 * Y2C;
                const float y23 = z * x * ir2;
                const float y24 = (x*x - y*y) * ir2 * 0.5f;
                const float t = radm * in0[b * CC + c];
                acc[0] = fmaf(t, y20, acc[0]);
                acc[1] = fmaf(t, y21, acc[1]);
                acc[2] = fmaf(t, y22, acc[2]);
                acc[3] = fmaf(t, y23, acc[3]);
                acc[4] = fmaf(t, y24, acc[4]);
            } else if (f == 3) {
                const float i10 = in1[(b * CC + c) * 3 + 0];
                const float i11 = in1[(b * CC + c) * 3 + 1];
                const float i12 = in1[(b * CC + c) * 3 + 2];
                acc[0] = fmaf(radm, ux*i10 + uy*i11 + uz*i12, acc[0]);
            } else { // f == 4: Levi-Civita -> cross(u, in1)
                const float i10 = in1[(b * CC + c) * 3 + 0];
                const float i11 = in1[(b * CC + c) * 3 + 1];
                const float i12 = in1[(b * CC + c) * 3 + 2];
                const float cx = uy*i12 - uz*i11;
                const float cy = uz*i10 - ux*i12;
                const float cz = ux*i11 - uy*i10;
                acc[0] = fmaf(radm, cx, acc[0]);
                acc[1] = fmaf(radm, cy, acc[1]);
                acc[2] = fmaf(radm, cz, acc[2]);
            }
        }
    }

    // ---- reduce over the 8 b-groups and write this filter's outputs ----
    const int nacc = (f == 0) ? 9 : (f == 1) ? 3 : (f == 2) ? 5 : (f == 3) ? 1 : 3;
    const int NC = NN * CC;  // 16384
    const int c = lane;

    for (int comp = 0; comp < nacc; ++comp) {
        __syncthreads();
        red[bg][lane] = acc[comp];
        __syncthreads();
        if (bg == 0) {
            float s = 0.f;
            #pragma unroll
            for (int g = 0; g < 8; ++g) s += red[g][lane];
            int idx;
            if (f == 0) {
                if (comp == 0)      idx = 0 * NC + a * CC + c;                         // o0_s
                else if (comp < 4)  idx = 2 * NC + 1 * NC * 3 + (a * CC + c) * 3 + (comp - 1); // o1_s
                else                idx = 11 * NC + 1 * NC * 5 + (a * CC + c) * 5 + (comp - 4); // o2_s
            } else if (f == 1) {
                idx = 2 * NC + 0 * NC * 3 + (a * CC + c) * 3 + comp;                  // o1_a
            } else if (f == 2) {
                idx = 11 * NC + 0 * NC * 5 + (a * CC + c) * 5 + comp;                 // o2_a
            } else if (f == 3) {
                idx = 1 * NC + a * CC + c;                                            // o0_b
            } else {
                idx = 2 * NC + 2 * NC * 3 + (a * CC + c) * 3 + comp;                  // o1_c
            }
            out[idx] = s;
        }
    }
}

extern "C" void kernel_launch(void* const* d_in, const int* in_sizes, int n_in,
                              void* d_out, int out_size, void* d_ws, size_t ws_size,
                              hipStream_t stream) {
    const float* in0 = (const float*)d_in[0];
    const float* in1 = (const float*)d_in[1];
    const float* in2 = (const float*)d_in[2];
    const float* rbf = (const float*)d_in[3];
    const float* rij = (const float*)d_in[4];

    TFNWeights W;
    for (int i = 0; i < 5; ++i) {
        W.w1[i] = (const float*)d_in[5 + 4 * i + 0];
        W.b1[i] = (const float*)d_in[5 + 4 * i + 1];
        W.w2[i] = (const float*)d_in[5 + 4 * i + 2];
        W.b2[i] = (const float*)d_in[5 + 4 * i + 3];
    }

    dim3 grid(NN, 5);
    dim3 block(256);
    hipLaunchKernelGGL(tfn_kernel, grid, block, 0, stream,
                       in0, in1, in2, rbf, rij, W, (float*)d_out);
}

// Round 2
// 231.205 us; speedup vs baseline: 1.2884x; 1.2884x over previous
//
#include <hip/hip_runtime.h>
#include <math.h>

#define NN 512
#define CC 32
#define RR 32
#define EPSF 1e-8f

// Filter ids: 0=f00 (scalar), 1=f01 (0x1->1), 2=f02 (0x2->2), 3=f10 (1x1->0), 4=f11 (1x1->1)

struct TFNWeights {
    const float* w1[5];
    const float* b1[5];
    const float* w2[5];
    const float* b2[5];
};

__global__ __launch_bounds__(256) void tfn_kernel(
    const float* __restrict__ in0,   // [N,C,1]
    const float* __restrict__ in1,   // [N,C,3]
    const float* __restrict__ in2,   // [N,C,5]
    const float* __restrict__ rbf,   // [N,N,R]
    const float* __restrict__ rij,   // [N,N,3]
    TFNWeights W,
    float* __restrict__ out)
{
    const int a    = blockIdx.x;
    const int f    = blockIdx.y;
    const int lane = threadIdx.x & 31;   // k in layer1, c in layer2/accum
    const int bg   = threadIdx.x >> 5;   // which b within the 8-wide tile

    // All in-loop LDS traffic is private to a 32-thread half-wave (bg):
    // written and read by the same lanes -> no __syncthreads needed, the
    // compiler's lgkmcnt waits give correct intra-wave ordering.
    __shared__ float rbfs[8][32];
    __shared__ float hs[8][32];
    __shared__ float red[8][9][32];

    // ---- cache this filter's weight rows in registers ----
    float w1row[32], w2row[32];
    {
        const float4* w1p = (const float4*)(W.w1[f] + lane * RR);
        const float4* w2p = (const float4*)(W.w2[f] + lane * RR);
        #pragma unroll
        for (int i = 0; i < 8; ++i) {
            float4 q = w1p[i];
            w1row[4*i+0] = q.x; w1row[4*i+1] = q.y; w1row[4*i+2] = q.z; w1row[4*i+3] = q.w;
            float4 p = w2p[i];
            w2row[4*i+0] = p.x; w2row[4*i+1] = p.y; w2row[4*i+2] = p.z; w2row[4*i+3] = p.w;
        }
    }
    const float b1v = W.b1[f][lane];
    const float b2v = W.b2[f][lane];

    float acc[9];
    #pragma unroll
    for (int i = 0; i < 9; ++i) acc[i] = 0.f;

    const float Y2C = 0.28867513459481287f;  // 1/(2*sqrt(3))

    const size_t rowbase = (size_t)a * NN;

    // prefetch tile 0
    float cur = rbf[(rowbase + bg) * RR + lane];
    float px = rij[(rowbase + bg) * 3 + 0];
    float py = rij[(rowbase + bg) * 3 + 1];
    float pz = rij[(rowbase + bg) * 3 + 2];

    #pragma unroll 2
    for (int tile = 0; tile < NN / 8; ++tile) {
        const int b = tile * 8 + bg;

        rbfs[bg][lane] = cur;            // half-wave private
        const float x = px, y = py, z = pz;

        // prefetch next tile while we compute this one
        if (tile + 1 < NN / 8) {
            const int nb = (tile + 1) * 8 + bg;
            cur = rbf[(rowbase + nb) * RR + lane];
            px = rij[(rowbase + nb) * 3 + 0];
            py = rij[(rowbase + nb) * 3 + 1];
            pz = rij[(rowbase + nb) * 3 + 2];
        }

        // ---- layer 1: h[k=lane] = relu(b1 + rbf . w1[k,:]) ----
        float h = b1v;
        #pragma unroll
        for (int r4 = 0; r4 < 8; ++r4) {
            float4 q = *(const float4*)&rbfs[bg][r4 * 4];
            h = fmaf(q.x, w1row[4*r4+0], h);
            h = fmaf(q.y, w1row[4*r4+1], h);
            h = fmaf(q.z, w1row[4*r4+2], h);
            h = fmaf(q.w, w1row[4*r4+3], h);
        }
        hs[bg][lane] = fmaxf(h, 0.f);    // half-wave private

        // ---- layer 2: rad[c=lane] = b2 + h . w2[c,:] ----
        float rad = b2v;
        #pragma unroll
        for (int k4 = 0; k4 < 8; ++k4) {
            float4 q = *(const float4*)&hs[bg][k4 * 4];
            rad = fmaf(q.x, w2row[4*k4+0], rad);
            rad = fmaf(q.y, w2row[4*k4+1], rad);
            rad = fmaf(q.z, w2row[4*k4+2], rad);
            rad = fmaf(q.w, w2row[4*k4+3], rad);
        }

        const int c = lane;
        const float d2 = x*x + y*y + z*z;
        const float d  = sqrtf(d2);

        if (f == 0) {
            const float i0 = in0[b * CC + c];
            acc[0] = fmaf(rad, i0, acc[0]);
            const float i10 = in1[(b * CC + c) * 3 + 0];
            const float i11 = in1[(b * CC + c) * 3 + 1];
            const float i12 = in1[(b * CC + c) * 3 + 2];
            acc[1] = fmaf(rad, i10, acc[1]);
            acc[2] = fmaf(rad, i11, acc[2]);
            acc[3] = fmaf(rad, i12, acc[3]);
            #pragma unroll
            for (int i = 0; i < 5; ++i) {
                acc[4 + i] = fmaf(rad, in2[(b * CC + c) * 5 + i], acc[4 + i]);
            }
        } else {
            const float m = (d >= EPSF) ? 1.f : 0.f;
            const float radm = rad * m;
            const float inv = 1.f / (d + EPSF);
            const float ux = x * inv, uy = y * inv, uz = z * inv;
            if (f == 1) {
                const float t = radm * in0[b * CC + c];
                acc[0] = fmaf(t, ux, acc[0]);
                acc[1] = fmaf(t, uy, acc[1]);
                acc[2] = fmaf(t, uz, acc[2]);
            } else if (f == 2) {
                const float ir2 = 1.f / fmaxf(d2, EPSF);
                const float y20 = x * y * ir2;
                const float y21 = y * z * ir2;
                const float y22 = (2.f*z*z - x*x - y*y) * ir2 * Y2C;
                const float y23 = z * x * ir2;
                const float y24 = (x*x - y*y) * ir2 * 0.5f;
                const float t = radm * in0[b * CC + c];
                acc[0] = fmaf(t, y20, acc[0]);
                acc[1] = fmaf(t, y21, acc[1]);
                acc[2] = fmaf(t, y22, acc[2]);
                acc[3] = fmaf(t, y23, acc[3]);
                acc[4] = fmaf(t, y24, acc[4]);
            } else if (f == 3) {
                const float i10 = in1[(b * CC + c) * 3 + 0];
                const float i11 = in1[(b * CC + c) * 3 + 1];
                const float i12 = in1[(b * CC + c) * 3 + 2];
                acc[0] = fmaf(radm, ux*i10 + uy*i11 + uz*i12, acc[0]);
            } else { // f == 4: Levi-Civita -> cross(u, in1)
                const float i10 = in1[(b * CC + c) * 3 + 0];
                const float i11 = in1[(b * CC + c) * 3 + 1];
                const float i12 = in1[(b * CC + c) * 3 + 2];
                const float cx = uy*i12 - uz*i11;
                const float cy = uz*i10 - ux*i12;
                const float cz = ux*i11 - uy*i10;
                acc[0] = fmaf(radm, cx, acc[0]);
                acc[1] = fmaf(radm, cy, acc[1]);
                acc[2] = fmaf(radm, cz, acc[2]);
            }
        }
    }

    // ---- reduce over the 8 b-groups (single barrier) and write outputs ----
    const int nacc = (f == 0) ? 9 : (f == 1) ? 3 : (f == 2) ? 5 : (f == 3) ? 1 : 3;
    const int NC = NN * CC;  // 16384
    const int c = lane;

    for (int comp = 0; comp < nacc; ++comp)
        red[bg][comp][lane] = acc[comp];
    __syncthreads();

    if (bg == 0) {
        for (int comp = 0; comp < nacc; ++comp) {
            float s = 0.f;
            #pragma unroll
            for (int g = 0; g < 8; ++g) s += red[g][comp][lane];
            int idx;
            if (f == 0) {
                if (comp == 0)      idx = 0 * NC + a * CC + c;                                  // o0_s
                else if (comp < 4)  idx = 2 * NC + 1 * NC * 3 + (a * CC + c) * 3 + (comp - 1);  // o1_s
                else                idx = 11 * NC + 1 * NC * 5 + (a * CC + c) * 5 + (comp - 4); // o2_s
            } else if (f == 1) {
                idx = 2 * NC + 0 * NC * 3 + (a * CC + c) * 3 + comp;                  // o1_a
            } else if (f == 2) {
                idx = 11 * NC + 0 * NC * 5 + (a * CC + c) * 5 + comp;                 // o2_a
            } else if (f == 3) {
                idx = 1 * NC + a * CC + c;                                            // o0_b
            } else {
                idx = 2 * NC + 2 * NC * 3 + (a * CC + c) * 3 + comp;                  // o1_c
            }
            out[idx] = s;
        }
    }
}

extern "C" void kernel_launch(void* const* d_in, const int* in_sizes, int n_in,
                              void* d_out, int out_size, void* d_ws, size_t ws_size,
                              hipStream_t stream) {
    const float* in0 = (const float*)d_in[0];
    const float* in1 = (const float*)d_in[1];
    const float* in2 = (const float*)d_in[2];
    const float* rbf = (const float*)d_in[3];
    const float* rij = (const float*)d_in[4];

    TFNWeights W;
    for (int i = 0; i < 5; ++i) {
        W.w1[i] = (const float*)d_in[5 + 4 * i + 0];
        W.b1[i] = (const float*)d_in[5 + 4 * i + 1];
        W.w2[i] = (const float*)d_in[5 + 4 * i + 2];
        W.b2[i] = (const float*)d_in[5 + 4 * i + 3];
    }

    dim3 grid(NN, 5);
    dim3 block(256);
    hipLaunchKernelGGL(tfn_kernel, grid, block, 0, stream,
                       in0, in1, in2, rbf, rij, W, (float*)d_out);
}

// Round 3
// 151.196 us; speedup vs baseline: 1.9701x; 1.5292x over previous
//
#include <hip/hip_runtime.h>
#include <math.h>

#define NN 512
#define CC 32
#define EPSF 1e-8f

typedef __attribute__((ext_vector_type(8))) short bf16x8;
typedef __attribute__((ext_vector_type(4))) float f32x4;

struct TFNWeights {
    const float* w1[5];
    const float* b1[5];
    const float* w2[5];
    const float* b2[5];
};

// fp32 -> bf16 bits, round-to-nearest-even
__device__ inline short f2bf(float f) {
    unsigned u = __float_as_uint(f);
    u += 0x7fffu + ((u >> 16) & 1u);
    return (short)(u >> 16);
}

// One block per a (512 threads = 8 waves). Each wave owns 64 b's (4 tiles of 16).
// MFMA 16x16x32_bf16 for both MLP layers; fragment maps (verified gfx950):
//   A: row = lane&15, k = 8*(lane>>4)+j    B: col = lane&15, k = 8*(lane>>4)+j
//   D: col = lane&15, row = 4*(lane>>4)+reg
__global__ __launch_bounds__(512, 2) void tfn_mfma(
    const float* __restrict__ in0,   // [N,C,1]
    const float* __restrict__ in1,   // [N,C,3]
    const float* __restrict__ in2,   // [N,C,5]
    const float* __restrict__ rbf,   // [N,N,32]
    const float* __restrict__ rij,   // [N,N,3]
    TFNWeights W,
    float* __restrict__ out)
{
    const int a    = blockIdx.x;
    const int tid  = threadIdx.x;
    const int w    = tid >> 6;     // wave 0..7
    const int lane = tid & 63;
    const int q    = lane >> 4;    // k-block quad 0..3
    const int ln   = lane & 15;

    // LDS: 25600 + 10240 + 4096 + 21504 = 61440 B
    __shared__ short wlds[5 * 2 * 32 * 40];  // [f][layer][n][k] bf16, row stride 40
    __shared__ short hlds[8][16 * 40];       // per-wave h tile [p][n], stride 40
    __shared__ float geom[8][16][8];         // per-wave: ux,uy,uz,y20..y24 (mask folded)
    __shared__ float red[8][21][32];         // final cross-wave reduction

    // ---- stage weights as bf16 into LDS (B-operand friendly: [n][k] k-contig) ----
    #pragma unroll
    for (int f = 0; f < 5; ++f) {
        for (int idx = tid; idx < 2048; idx += 512) {
            const int k = idx & 31, n = (idx >> 5) & 31, layer = idx >> 10;
            const float* src = layer ? W.w2[f] : W.w1[f];
            wlds[((f * 2 + layer) * 32 + n) * 40 + k] = f2bf(src[n * 32 + k]);
        }
    }
    // biases -> registers (used as MFMA C-in)
    float bias1[5][2], bias2[5][2];
    #pragma unroll
    for (int f = 0; f < 5; ++f) {
        bias1[f][0] = W.b1[f][ln];      bias1[f][1] = W.b1[f][16 + ln];
        bias2[f][0] = W.b2[f][ln];      bias2[f][1] = W.b2[f][16 + ln];
    }
    __syncthreads();

    float acc[2][21];
    #pragma unroll
    for (int h = 0; h < 2; ++h)
        #pragma unroll
        for (int cmp = 0; cmp < 21; ++cmp) acc[h][cmp] = 0.f;

    const size_t rowbase = (size_t)a * NN;
    const float Y2C = 0.28867513459481287f;  // 1/(2*sqrt(3))

    f32x4 radL[5], radH[5];

    for (int t = 0; t < 4; ++t) {
        const int b0 = w * 64 + t * 16;

        // ---- per-tile geometry (16 lanes; mask folded into u and y2) ----
        if (lane < 16) {
            const int b = b0 + lane;
            const float* rp = rij + (rowbase + b) * 3;
            const float x = rp[0], y = rp[1], z = rp[2];
            const float d2 = x * x + y * y + z * z;
            const float d  = sqrtf(d2);
            const float m  = (d >= EPSF) ? 1.f : 0.f;
            const float inv = m / (d + EPSF);
            const float ir2 = m / fmaxf(d2, EPSF);
            float* gp = &geom[w][lane][0];
            gp[0] = x * inv; gp[1] = y * inv; gp[2] = z * inv;
            gp[3] = x * y * ir2;
            gp[4] = y * z * ir2;
            gp[5] = (2.f * z * z - x * x - y * y) * (ir2 * Y2C);
            gp[6] = z * x * ir2;
            gp[7] = (x * x - y * y) * (ir2 * 0.5f);
        }

        // ---- rbf A-fragment (shared across all 5 filters) ----
        const float* rsrc = rbf + (rowbase + b0 + ln) * 32 + q * 8;
        const float4 ra = *(const float4*)rsrc;
        const float4 rb = *(const float4*)(rsrc + 4);
        union { bf16x8 v; short s[8]; } rfu;
        rfu.s[0] = f2bf(ra.x); rfu.s[1] = f2bf(ra.y);
        rfu.s[2] = f2bf(ra.z); rfu.s[3] = f2bf(ra.w);
        rfu.s[4] = f2bf(rb.x); rfu.s[5] = f2bf(rb.y);
        rfu.s[6] = f2bf(rb.z); rfu.s[7] = f2bf(rb.w);
        const bf16x8 rbfF = rfu.v;

        // ---- 5 radial MLPs via MFMA ----
        short* hw = &hlds[w][0];
        #pragma unroll
        for (int f = 0; f < 5; ++f) {
            const bf16x8 w1lo = *(const bf16x8*)&wlds[((f * 2 + 0) * 32 + ln) * 40 + q * 8];
            const bf16x8 w1hi = *(const bf16x8*)&wlds[((f * 2 + 0) * 32 + 16 + ln) * 40 + q * 8];
            f32x4 d0, d1;
            d0[0] = d0[1] = d0[2] = d0[3] = bias1[f][0];
            d1[0] = d1[1] = d1[2] = d1[3] = bias1[f][1];
            d0 = __builtin_amdgcn_mfma_f32_16x16x32_bf16(rbfF, w1lo, d0, 0, 0, 0);
            d1 = __builtin_amdgcn_mfma_f32_16x16x32_bf16(rbfF, w1hi, d1, 0, 0, 0);
            // relu + cvt, transpose h through wave-private LDS
            #pragma unroll
            for (int rr = 0; rr < 4; ++rr) {
                hw[(q * 4 + rr) * 40 + ln]      = f2bf(fmaxf(d0[rr], 0.f));
                hw[(q * 4 + rr) * 40 + 16 + ln] = f2bf(fmaxf(d1[rr], 0.f));
            }
            const bf16x8 hF = *(const bf16x8*)&hw[ln * 40 + q * 8];
            const bf16x8 w2lo = *(const bf16x8*)&wlds[((f * 2 + 1) * 32 + ln) * 40 + q * 8];
            const bf16x8 w2hi = *(const bf16x8*)&wlds[((f * 2 + 1) * 32 + 16 + ln) * 40 + q * 8];
            f32x4 r0, r1;
            r0[0] = r0[1] = r0[2] = r0[3] = bias2[f][0];
            r1[0] = r1[1] = r1[2] = r1[3] = bias2[f][1];
            r0 = __builtin_amdgcn_mfma_f32_16x16x32_bf16(hF, w2lo, r0, 0, 0, 0);
            r1 = __builtin_amdgcn_mfma_f32_16x16x32_bf16(hF, w2hi, r1, 0, 0, 0);
            radL[f] = r0; radH[f] = r1;
        }

        // ---- aggregation (VALU): each lane owns 4 pairs x 2 channels ----
        #pragma unroll
        for (int rr = 0; rr < 4; ++rr) {
            const int p = q * 4 + rr;
            const int b = b0 + p;
            const float4 g0 = *(const float4*)&geom[w][p][0];
            const float4 g1 = *(const float4*)&geom[w][p][4];
            const float ux = g0.x, uy = g0.y, uz = g0.z;
            const float y20 = g0.w, y21 = g1.x, y22 = g1.y, y23 = g1.z, y24 = g1.w;
            #pragma unroll
            for (int h = 0; h < 2; ++h) {
                const int c = ln + h * 16;
                const float s00 = h ? radH[0][rr] : radL[0][rr];
                const float s01 = h ? radH[1][rr] : radL[1][rr];
                const float s02 = h ? radH[2][rr] : radL[2][rr];
                const float s10 = h ? radH[3][rr] : radL[3][rr];
                const float s11 = h ? radH[4][rr] : radL[4][rr];
                const float i0  = in0[b * CC + c];
                const float* i1p = in1 + (b * CC + c) * 3;
                const float i10 = i1p[0], i11 = i1p[1], i12 = i1p[2];
                const float* i2p = in2 + (b * CC + c) * 5;
                // o0_s
                acc[h][0] = fmaf(s00, i0, acc[h][0]);
                // o1_s
                acc[h][5] = fmaf(s00, i10, acc[h][5]);
                acc[h][6] = fmaf(s00, i11, acc[h][6]);
                acc[h][7] = fmaf(s00, i12, acc[h][7]);
                // o2_s
                #pragma unroll
                for (int j = 0; j < 5; ++j)
                    acc[h][16 + j] = fmaf(s00, i2p[j], acc[h][16 + j]);
                // o1_a: u * (r01 * in0)
                const float t01 = s01 * i0;
                acc[h][2] = fmaf(t01, ux, acc[h][2]);
                acc[h][3] = fmaf(t01, uy, acc[h][3]);
                acc[h][4] = fmaf(t01, uz, acc[h][4]);
                // o2_a: y2 * (r02 * in0)
                const float t02 = s02 * i0;
                acc[h][11] = fmaf(t02, y20, acc[h][11]);
                acc[h][12] = fmaf(t02, y21, acc[h][12]);
                acc[h][13] = fmaf(t02, y22, acc[h][13]);
                acc[h][14] = fmaf(t02, y23, acc[h][14]);
                acc[h][15] = fmaf(t02, y24, acc[h][15]);
                // o0_b: r10 * (u . in1)
                const float dt = fmaf(uz, i12, fmaf(uy, i11, ux * i10));
                acc[h][1] = fmaf(s10, dt, acc[h][1]);
                // o1_c: r11 * (u x in1)
                const float cx = fmaf(uy, i12, -(uz * i11));
                const float cy = fmaf(uz, i10, -(ux * i12));
                const float cz = fmaf(ux, i11, -(uy * i10));
                acc[h][8]  = fmaf(s11, cx, acc[h][8]);
                acc[h][9]  = fmaf(s11, cy, acc[h][9]);
                acc[h][10] = fmaf(s11, cz, acc[h][10]);
            }
        }
    }

    // ---- reduce quads within wave, then waves via LDS ----
    #pragma unroll
    for (int h = 0; h < 2; ++h) {
        #pragma unroll
        for (int cmp = 0; cmp < 21; ++cmp) {
            float v = acc[h][cmp];
            v += __shfl_down(v, 32);
            v += __shfl_down(v, 16);
            if (lane < 16) red[w][cmp][ln + h * 16] = v;
        }
    }
    __syncthreads();

    const int NC = NN * CC;
    for (int e = tid; e < 21 * 32; e += 512) {
        const int cmp = e >> 5, c = e & 31;
        float s = 0.f;
        #pragma unroll
        for (int g = 0; g < 8; ++g) s += red[g][cmp][c];
        int idx;
        if (cmp == 0)       idx = a * CC + c;                               // o0_s
        else if (cmp == 1)  idx = NC + a * CC + c;                          // o0_b
        else if (cmp < 5)   idx = 2 * NC + (a * CC + c) * 3 + (cmp - 2);    // o1_a
        else if (cmp < 8)   idx = 2 * NC + 3 * NC + (a * CC + c) * 3 + (cmp - 5);   // o1_s
        else if (cmp < 11)  idx = 2 * NC + 6 * NC + (a * CC + c) * 3 + (cmp - 8);   // o1_c
        else if (cmp < 16)  idx = 11 * NC + (a * CC + c) * 5 + (cmp - 11);          // o2_a
        else                idx = 11 * NC + 5 * NC + (a * CC + c) * 5 + (cmp - 16); // o2_s
        out[idx] = s;
    }
}

extern "C" void kernel_launch(void* const* d_in, const int* in_sizes, int n_in,
                              void* d_out, int out_size, void* d_ws, size_t ws_size,
                              hipStream_t stream) {
    const float* in0 = (const float*)d_in[0];
    const float* in1 = (const float*)d_in[1];
    const float* in2 = (const float*)d_in[2];
    const float* rbf = (const float*)d_in[3];
    const float* rij = (const float*)d_in[4];

    TFNWeights W;
    for (int i = 0; i < 5; ++i) {
        W.w1[i] = (const float*)d_in[5 + 4 * i + 0];
        W.b1[i] = (const float*)d_in[5 + 4 * i + 1];
        W.w2[i] = (const float*)d_in[5 + 4 * i + 2];
        W.b2[i] = (const float*)d_in[5 + 4 * i + 3];
    }

    hipLaunchKernelGGL(tfn_mfma, dim3(NN), dim3(512), 0, stream,
                       in0, in1, in2, rbf, rij, W, (float*)d_out);
}